// Round 1
// baseline (654.385 us; speedup 1.0000x reference)
//
#include <hip/hip_runtime.h>

#define N_ROWS 200000
#define P 576
#define P4 144   // P / 4 float4 column-groups
#define GRID1 1024

// ws layout: S1[P] floats, then S2[P] floats (zeroed before launch)

__global__ __launch_bounds__(576) void colsum_kernel(const float4* __restrict__ X4,
                                                     float* __restrict__ S1,
                                                     float* __restrict__ S2) {
    const int x = threadIdx.x;   // [0,144): float4 column group
    const int y = threadIdx.y;   // [0,4):   row offset within block stripe

    float4 s1 = make_float4(0.f, 0.f, 0.f, 0.f);
    float4 s2 = make_float4(0.f, 0.f, 0.f, 0.f);

    for (int r = blockIdx.x * 4 + y; r < N_ROWS; r += GRID1 * 4) {
        float4 v = X4[(size_t)r * P4 + x];
        s1.x += v.x;      s1.y += v.y;      s1.z += v.z;      s1.w += v.w;
        s2.x += v.x * v.x; s2.y += v.y * v.y; s2.z += v.z * v.z; s2.w += v.w * v.w;
    }

    __shared__ float4 sh1[4][P4];
    __shared__ float4 sh2[4][P4];
    sh1[y][x] = s1;
    sh2[y][x] = s2;
    __syncthreads();

    if (y == 0) {
        #pragma unroll
        for (int i = 1; i < 4; ++i) {
            float4 a = sh1[i][x], b = sh2[i][x];
            s1.x += a.x; s1.y += a.y; s1.z += a.z; s1.w += a.w;
            s2.x += b.x; s2.y += b.y; s2.z += b.z; s2.w += b.w;
        }
        atomicAdd(&S1[4 * x + 0], s1.x);
        atomicAdd(&S1[4 * x + 1], s1.y);
        atomicAdd(&S1[4 * x + 2], s1.z);
        atomicAdd(&S1[4 * x + 3], s1.w);
        atomicAdd(&S2[4 * x + 0], s2.x);
        atomicAdd(&S2[4 * x + 1], s2.y);
        atomicAdd(&S2[4 * x + 2], s2.z);
        atomicAdd(&S2[4 * x + 3], s2.w);
    }
}

__global__ __launch_bounds__(256) void project_kernel(const float* __restrict__ S1,
                                                      const float* __restrict__ S2,
                                                      const float* __restrict__ mu,
                                                      const float* __restrict__ W,
                                                      float* __restrict__ out) {
    const int tid = threadIdx.x;
    const float invN = 1.0f / (float)N_ROWS;
    float acc0 = 0.f, acc1 = 0.f, acc2 = 0.f, acc3 = 0.f;

    for (int p = tid; p < P; p += 256) {
        float m    = S1[p] * invN;
        float mom2 = S2[p] * invN - m * m;
        int j = 3 * p;
        float c0 = m    - mu[j];
        float c1 = 0.f  - mu[j + 1];
        float c2 = mom2 - mu[j + 2];
        const float* w0 = &W[(size_t)j * 4];
        acc0 += c0 * w0[0] + c1 * w0[4] + c2 * w0[8];
        acc1 += c0 * w0[1] + c1 * w0[5] + c2 * w0[9];
        acc2 += c0 * w0[2] + c1 * w0[6] + c2 * w0[10];
        acc3 += c0 * w0[3] + c1 * w0[7] + c2 * w0[11];
    }

    // wave-64 butterfly reduction
    #pragma unroll
    for (int off = 32; off > 0; off >>= 1) {
        acc0 += __shfl_down(acc0, off);
        acc1 += __shfl_down(acc1, off);
        acc2 += __shfl_down(acc2, off);
        acc3 += __shfl_down(acc3, off);
    }

    __shared__ float sacc[4][4];  // [wave][k]
    const int wave = tid >> 6;
    const int lane = tid & 63;
    if (lane == 0) {
        sacc[wave][0] = acc0;
        sacc[wave][1] = acc1;
        sacc[wave][2] = acc2;
        sacc[wave][3] = acc3;
    }
    __syncthreads();
    if (tid < 4) {
        float r = sacc[0][tid] + sacc[1][tid] + sacc[2][tid] + sacc[3][tid];
        out[tid] = r;
    }
}

extern "C" void kernel_launch(void* const* d_in, const int* in_sizes, int n_in,
                              void* d_out, int out_size, void* d_ws, size_t ws_size,
                              hipStream_t stream) {
    const float* X  = (const float*)d_in[0];   // (200000, 576) fp32
    const float* mu = (const float*)d_in[1];   // (1728,)
    const float* W  = (const float*)d_in[2];   // (1728, 4)
    float* out = (float*)d_out;                // (4,)

    float* S1 = (float*)d_ws;
    float* S2 = S1 + P;

    hipMemsetAsync(d_ws, 0, 2 * P * sizeof(float), stream);

    dim3 block(P4, 4);  // 576 threads = 9 waves
    colsum_kernel<<<GRID1, block, 0, stream>>>((const float4*)X, S1, S2);
    project_kernel<<<1, 256, 0, stream>>>(S1, S2, mu, W, out);
}